// Round 6
// baseline (694.320 us; speedup 1.0000x reference)
//
#include <hip/hip_runtime.h>

typedef unsigned int u32;
typedef unsigned short u16;
typedef __attribute__((ext_vector_type(8))) short short8;   // 8 bf16 (4 VGPRs)
typedef __attribute__((ext_vector_type(4))) float f32x4;

#define DEV __device__ __forceinline__
#define LOG2E 1.44269504089f

DEV u16 f2bf(float f) {
    u32 u = __float_as_uint(f);
    return (u16)((u + 0x7FFFu + ((u >> 16) & 1u)) >> 16);
}
DEV float bf2f(u16 h) { return __uint_as_float(((u32)h) << 16); }
DEV float frcp(float x) { return __builtin_amdgcn_rcpf(x); }
DEV float fexp2(float x) {
#if __has_builtin(__builtin_amdgcn_exp2f)
    return __builtin_amdgcn_exp2f(x);
#else
    return exp2f(x);
#endif
}
DEV u32 pack_bf16(float a, float b) {
#if __has_builtin(__builtin_amdgcn_cvt_pk_bf16_f32)
    auto v = __builtin_amdgcn_cvt_pk_bf16_f32(a, b);   // lo=a, hi=b
    u32 r; __builtin_memcpy(&r, &v, 4); return r;
#else
    return (u32)f2bf(a) | ((u32)f2bf(b) << 16);
#endif
}

// ---------------------------------------------------------------------------
// K2 (R6): FUSED embedding-gather + input-projection + LSTM recurrence.
// 8 blocks = 2 dirs x 4 batch-groups(16).  z_t = Wih*e_t + Whh*h_{t-1}: one
// K=256 MFMA chain (8 frags) per tile, acc initialized from the bias frag.
// No X tensor.  e rows gathered from HBM 2 steps ahead (regs) -> bf16 LDS
// ring of 4 tiles.  h history in an 8-slot LDS ring, flushed to global as
// coalesced dwordx4 bursts every 8 steps -> in-loop vmem FIFO holds only the
// e-gather loads.  In-loop barriers are lgkm-only.  Weights (2x16 A-frags,
// log2e-folded) stay resident in the unified VGPR/AGPR file.
// ---------------------------------------------------------------------------
__global__ __launch_bounds__(512) void k_lstm(
    const int* __restrict__ sent, const float* __restrict__ emb,
    const float* __restrict__ h0, const float* __restrict__ c0,
    const float* __restrict__ whhf, const float* __restrict__ whhb,
    const float* __restrict__ wihf, const float* __restrict__ wihb,
    const float* __restrict__ bihf, const float* __restrict__ bhhf,
    const float* __restrict__ bihb, const float* __restrict__ bhhb,
    u16* __restrict__ hfo, u16* __restrict__ hbo)
{
    const int d  = blockIdx.x >> 2, g4 = blockIdx.x & 3;
    const float* whh = d ? whhb : whhf;
    const float* wih = d ? wihb : wihf;
    const float* bih = d ? bihb : bihf;
    const float* bhh = d ? bhhb : bhhf;
    u16* ho = d ? hbo : hfo;
    const int tid = threadIdx.x;
    const int w = tid >> 6, lane = tid & 63;
    const int rg = lane >> 4, cn = lane & 15;
    const int row16 = tid >> 5, col32 = tid & 31;
    const int chb = 16 * w + rg * 4;
    const int b = g4 * 16 + cn;

    __shared__ int stoks[512 * 17];                    // tokens, 17-pad = conflict-free
    __shared__ __align__(16) u16 ebuf[4][16][136];     // e-tile ring (bf16)
    __shared__ __align__(16) u16 hring[8][16][136];    // h history ring (bf16)

    // A-fragments: Whh and Wih, both pre-scaled by log2e.  A[m=lane&15][k=rg*8+j]
    short8 ah[4][4], ae[4][4];
    #pragma unroll
    for (int mi = 0; mi < 4; ++mi) {
        int gate = 16 * (w + 8 * mi) + cn;
        #pragma unroll
        for (int kt = 0; kt < 4; ++kt) {
            const float* ph = whh + (size_t)gate * 128 + kt * 32 + rg * 8;
            const float* pe = wih + (size_t)gate * 128 + kt * 32 + rg * 8;
            float4 h0v = *(const float4*)ph, h1v = *(const float4*)(ph + 4);
            float4 e0v = *(const float4*)pe, e1v = *(const float4*)(pe + 4);
            union { short8 v; u32 u[4]; } sh, se;
            sh.u[0] = pack_bf16(h0v.x * LOG2E, h0v.y * LOG2E);
            sh.u[1] = pack_bf16(h0v.z * LOG2E, h0v.w * LOG2E);
            sh.u[2] = pack_bf16(h1v.x * LOG2E, h1v.y * LOG2E);
            sh.u[3] = pack_bf16(h1v.z * LOG2E, h1v.w * LOG2E);
            se.u[0] = pack_bf16(e0v.x * LOG2E, e0v.y * LOG2E);
            se.u[1] = pack_bf16(e0v.z * LOG2E, e0v.w * LOG2E);
            se.u[2] = pack_bf16(e1v.x * LOG2E, e1v.y * LOG2E);
            se.u[3] = pack_bf16(e1v.z * LOG2E, e1v.w * LOG2E);
            ah[mi][kt] = sh.v;
            ae[mi][kt] = se.v;
        }
    }
    f32x4 bs4[4];                                      // bias C-operand frags
    #pragma unroll
    for (int mi = 0; mi < 4; ++mi)
        #pragma unroll
        for (int r = 0; r < 4; ++r) {
            int g = 16 * (w + 8 * mi) + 4 * rg + r;
            bs4[mi][r] = (bih[g] + bhh[g]) * LOG2E;
        }
    float cst[4];
    {
        float4 cv = *(const float4*)(c0 + ((size_t)d * 64 + b) * 128 + chb);
        cst[0]=cv.x; cst[1]=cv.y; cst[2]=cv.z; cst[3]=cv.w;
    }
    {   // token preload: thread tid owns s=tid (16 ints), b32 writes conflict-free
        int s = tid;
        const int4* sp = (const int4*)(sent + s * 64 + g4 * 16);
        int4 t0 = sp[0], t1 = sp[1], t2 = sp[2], t3 = sp[3];
        int* dst = &stoks[s * 17];
        dst[0]=t0.x; dst[1]=t0.y; dst[2]=t0.z; dst[3]=t0.w;
        dst[4]=t1.x; dst[5]=t1.y; dst[6]=t1.z; dst[7]=t1.w;
        dst[8]=t2.x; dst[9]=t2.y; dst[10]=t2.z; dst[11]=t2.w;
        dst[12]=t3.x; dst[13]=t3.y; dst[14]=t3.z; dst[15]=t3.w;
    }
    {   // h0 into ring slot 7 ( = step -1 )
        float4 hv = *(const float4*)(h0 + ((size_t)d * 64 + b) * 128 + chb);
        uint2 st0;
        st0.x = pack_bf16(hv.x, hv.y);
        st0.y = pack_bf16(hv.z, hv.w);
        *(uint2*)&hring[7][cn][chb] = st0;
    }
    // prime ebuf[0..1] = e(step 0,1); pend regs = raw e(step 2,3)
    #pragma unroll
    for (int k = 0; k < 2; ++k) {
        int s = d ? (511 - k) : k;
        int tok = sent[s * 64 + g4 * 16 + row16];
        float4 ev = *(const float4*)(emb + (size_t)tok * 128 + col32 * 4);
        uint2 wv; wv.x = pack_bf16(ev.x, ev.y); wv.y = pack_bf16(ev.z, ev.w);
        *(uint2*)&ebuf[k][row16][col32 * 4] = wv;
    }
    float4 pA, pB;
    { int s = d ? 509 : 2; int tok = sent[s*64 + g4*16 + row16];
      pA = *(const float4*)(emb + (size_t)tok * 128 + col32 * 4); }
    { int s = d ? 508 : 3; int tok = sent[s*64 + g4*16 + row16];
      pB = *(const float4*)(emb + (size_t)tok * 128 + col32 * 4); }
    __syncthreads();

    // One step: MFMA(K=256, acc=bias) -> cell -> h to ring; e-pipe: cvt PEND
    // (loaded 2 steps ago) into ebuf[(U+2)&3], reload PEND for t+4.
#define SUB(U, PEND)                                                         \
    {                                                                        \
        const int t = it * 8 + U;                                            \
        short8 hb[4], eb[4];                                                 \
        _Pragma("unroll") for (int kt = 0; kt < 4; ++kt) {                   \
            hb[kt] = *(const short8*)&hring[(U + 7) & 7][cn][kt*32 + rg*8];  \
            eb[kt] = *(const short8*)&ebuf[U & 3][cn][kt*32 + rg*8];         \
        }                                                                    \
        f32x4 z[4];                                                          \
        _Pragma("unroll") for (int mi = 0; mi < 4; ++mi) {                   \
            f32x4 acc = bs4[mi];                                             \
            _Pragma("unroll") for (int kt = 0; kt < 4; ++kt)                 \
                acc = __builtin_amdgcn_mfma_f32_16x16x32_bf16(               \
                    ah[mi][kt], hb[kt], acc, 0, 0, 0);                       \
            _Pragma("unroll") for (int kt = 0; kt < 4; ++kt)                 \
                acc = __builtin_amdgcn_mfma_f32_16x16x32_bf16(               \
                    ae[mi][kt], eb[kt], acc, 0, 0, 0);                       \
            z[mi] = acc;                                                     \
        }                                                                    \
        {                                                                    \
            uint2 wv; wv.x = pack_bf16(PEND.x, PEND.y);                      \
            wv.y = pack_bf16(PEND.z, PEND.w);                                \
            *(uint2*)&ebuf[(U + 2) & 3][row16][col32 * 4] = wv;              \
            int s_ = d ? (511 - (t + 4)) : (t + 4);                          \
            s_ = s_ < 0 ? 0 : (s_ > 511 ? 511 : s_);                         \
            int tok = stoks[s_ * 17 + row16];                                \
            PEND = *(const float4*)(emb + (size_t)tok * 128 + col32 * 4);    \
        }                                                                    \
        float hnew[4];                                                       \
        _Pragma("unroll") for (int r = 0; r < 4; ++r) {                      \
            float zi = z[0][r], zf = z[1][r], zg = z[2][r], zo = z[3][r];    \
            float ei = fexp2(-zi);                                           \
            float ef = fexp2(-zf);                                           \
            float eo = fexp2(-zo);                                           \
            float eg = fexp2(fminf(zg + zg, 126.f));                         \
            float A = 1.f + ei, F = 1.f + ef, G = 1.f + eg, O = 1.f + eo;    \
            float AG = A * G;                                                \
            float num = fmaf(cst[r], AG, (eg - 1.f) * F);                    \
            float cc  = num * frcp(F * AG);                                  \
            cst[r] = cc;                                                     \
            float ec = fexp2(fminf(2.885390082f * cc, 126.f));               \
            hnew[r] = (ec - 1.f) * frcp(fmaf(O, ec, O));                     \
        }                                                                    \
        uint2 st2;                                                           \
        st2.x = pack_bf16(hnew[0], hnew[1]);                                 \
        st2.y = pack_bf16(hnew[2], hnew[3]);                                 \
        *(uint2*)&hring[U & 7][cn][chb] = st2;                               \
        asm volatile("s_waitcnt lgkmcnt(0)\n\ts_barrier" ::: "memory");      \
    }

    for (int it = 0; it < 64; ++it) {
        SUB(0, pA); SUB(1, pB); SUB(2, pA); SUB(3, pB);
        SUB(4, pA); SUB(5, pB); SUB(6, pA); SUB(7, pB);
        // flush steps it*8 .. it*8+7 (slots 0..7) to global, coalesced x4
        #pragma unroll
        for (int c = 0; c < 4; ++c) {
            int chunk = c * 512 + tid;
            int slot = chunk >> 8, rw = (chunk >> 4) & 15, part = chunk & 15;
            uint4 v = *(const uint4*)&hring[slot][rw][part * 8];
            int s_ = d ? (511 - (it * 8 + slot)) : (it * 8 + slot);
            *(uint4*)(ho + ((size_t)s_ * 64 + g4 * 16 + rw) * 128 + part * 8) = v;
        }
        // protect ring slots from next iter's writes until flush reads done
        asm volatile("s_waitcnt lgkmcnt(0)\n\ts_barrier" ::: "memory");
    }
#undef SUB
}

// ---------------------------------------------------------------------------
// K3: feats[s,b,t] = [hf|hb] . w_out[t] + b_out[t].   block handles 32 pos.
// ---------------------------------------------------------------------------
__global__ __launch_bounds__(256) void k_feats(
    const u16* __restrict__ hf, const u16* __restrict__ hb,
    const float* __restrict__ wout, const float* __restrict__ bout,
    float* __restrict__ feats)
{
    __shared__ u16 sf[32][136], sb[32][136];
    __shared__ float wo[7][260];
    __shared__ float bo[8];
    int tid = threadIdx.x;
    int pos0 = blockIdx.x * 32;
    {
        int r = tid >> 3, cc = (tid & 7) * 16;
        const uint4* pf = (const uint4*)(hf + (size_t)(pos0 + r) * 128 + cc);
        const uint4* pb = (const uint4*)(hb + (size_t)(pos0 + r) * 128 + cc);
        *(uint4*)&sf[r][cc]     = pf[0];
        *(uint4*)&sf[r][cc + 8] = pf[1];
        *(uint4*)&sb[r][cc]     = pb[0];
        *(uint4*)&sb[r][cc + 8] = pb[1];
    }
    for (int i = tid; i < 1792; i += 256) wo[i >> 8][i & 255] = wout[i];
    if (tid < 7) bo[tid] = bout[tid];
    __syncthreads();
    int pp = tid >> 3, tt = tid & 7;
    if (tt < 7) {
        float acc = bo[tt];
        #pragma unroll 4
        for (int ch = 0; ch < 128; ++ch)
            acc += bf2f(sf[pp][ch]) * wo[tt][ch]
                 + bf2f(sb[pp][ch]) * wo[tt][128 + ch];
        feats[(size_t)(pos0 + pp) * 7 + tt] = acc;
    }
}

// ---------------------------------------------------------------------------
// K4a: CRF chunk fold.  block=(b, chunk of 64 steps).
// ---------------------------------------------------------------------------
__global__ __launch_bounds__(64) void k_crf_chunk(
    const float* __restrict__ feats, const float* __restrict__ trans,
    float* __restrict__ chunkM)
{
    int b = blockIdx.x >> 3, c = blockIdx.x & 7;
    int lane = threadIdx.x;
    int i = lane >> 3, j = lane & 7;
    __shared__ float M[8][8];
    __shared__ float fl[64][8];
    int s0 = c * 64;
    for (int idx = lane; idx < 448; idx += 64) {
        int ss = idx / 7, jj = idx - ss * 7;
        fl[ss][jj] = feats[(size_t)((s0 + ss) * 64 + b) * 7 + jj];
    }
    float tc[7];
    #pragma unroll
    for (int k = 0; k < 7; ++k) tc[k] = (j < 7) ? trans[k * 7 + j] : 0.f;
    __syncthreads();
    M[i][j] = (i < 7 && j < 7) ? (trans[i * 7 + j] + fl[0][j]) : -1e30f;
    __syncthreads();
    for (int ss = 1; ss < 64; ++ss) {
        float4 m0 = *(const float4*)&M[i][0];
        float4 m1 = *(const float4*)&M[i][4];
        float v0 = m0.x + tc[0], v1 = m0.y + tc[1], v2 = m0.z + tc[2];
        float v3 = m0.w + tc[3], v4 = m1.x + tc[4], v5 = m1.y + tc[5];
        float v6 = m1.z + tc[6];
        float mx = fmaxf(fmaxf(fmaxf(v0, v1), fmaxf(v2, v3)),
                         fmaxf(fmaxf(v4, v5), v6));
        float sm = __expf(v0 - mx) + __expf(v1 - mx) + __expf(v2 - mx)
                 + __expf(v3 - mx) + __expf(v4 - mx) + __expf(v5 - mx)
                 + __expf(v6 - mx);
        float r = mx + __logf(sm) + fl[ss][j];
        __syncthreads();
        if (i < 7 && j < 7) M[i][j] = r;
        __syncthreads();
    }
    if (i < 7 && j < 7)
        chunkM[(size_t)(b * 8 + c) * 49 + i * 7 + j] = M[i][j];
}

// ---------------------------------------------------------------------------
// K4b: fold 8 chunk matrices + alpha0 + STOP row; gold score; atomicAdd.
// ---------------------------------------------------------------------------
__global__ __launch_bounds__(64) void k_crf_final(
    const float* __restrict__ chunkM, const float* __restrict__ trans,
    const int* __restrict__ tags, const float* __restrict__ feats,
    float* __restrict__ out)
{
    int b = blockIdx.x;
    int lane = threadIdx.x;
    __shared__ float P[8][49];
    __shared__ float Tl[49];
    __shared__ float av[2][8];
    __shared__ int   tg[512];
    for (int idx = lane; idx < 392; idx += 64)
        P[idx / 49][idx % 49] = chunkM[(size_t)b * 392 + idx];
    if (lane < 49) Tl[lane] = trans[lane];
    for (int idx = lane; idx < 512; idx += 64) tg[idx] = tags[(size_t)b * 512 + idx];
    if (lane < 8) av[0][lane] = (lane == 5) ? 0.f : -1e4f;
    __syncthreads();
    int cur = 0;
    for (int cch = 0; cch < 8; ++cch) {
        if (lane < 7) {
            float vv[7], mx = -1e30f;
            #pragma unroll
            for (int ii = 0; ii < 7; ++ii) {
                vv[ii] = av[cur][ii] + P[cch][ii * 7 + lane];
                mx = fmaxf(mx, vv[ii]);
            }
            float sm = 0.f;
            #pragma unroll
            for (int ii = 0; ii < 7; ++ii) sm += __expf(vv[ii] - mx);
            av[cur ^ 1][lane] = mx + __logf(sm);
        }
        __syncthreads();
        cur ^= 1;
    }
    float mx = -1e30f, uu[7];
    #pragma unroll
    for (int jj = 0; jj < 7; ++jj) {
        uu[jj] = av[cur][jj] + Tl[6 * 7 + jj];
        mx = fmaxf(mx, uu[jj]);
    }
    float sm = 0.f;
    #pragma unroll
    for (int jj = 0; jj < 7; ++jj) sm += __expf(uu[jj] - mx);
    float fwd = mx + __logf(sm);
    float acc = 0.f;
    for (int ss = lane; ss < 512; ss += 64) {
        int tn = tg[ss];
        int tp = (ss == 0) ? 5 : tg[ss - 1];
        acc += Tl[tn * 7 + tp] + feats[(size_t)(ss * 64 + b) * 7 + tn];
    }
    #pragma unroll
    for (int mk = 32; mk >= 1; mk >>= 1) acc += __shfl_xor(acc, mk, 64);
    if (lane == 0) {
        float gold = acc + Tl[6 * 7 + tg[511]];
        atomicAdd(out, (fwd - gold) * (1.0f / 64.0f));
    }
}

// ---------------------------------------------------------------------------
extern "C" void kernel_launch(void* const* d_in, const int* in_sizes, int n_in,
                              void* d_out, int out_size, void* d_ws, size_t ws_size,
                              hipStream_t stream) {
    const int*   sent = (const int*)d_in[0];
    const int*   tags = (const int*)d_in[1];
    const float* h0   = (const float*)d_in[2];
    const float* c0   = (const float*)d_in[3];
    const float* emb  = (const float*)d_in[4];
    const float* wihf = (const float*)d_in[5];
    const float* whhf = (const float*)d_in[6];
    const float* bihf = (const float*)d_in[7];
    const float* bhhf = (const float*)d_in[8];
    const float* wihb = (const float*)d_in[9];
    const float* whhb = (const float*)d_in[10];
    const float* bihb = (const float*)d_in[11];
    const float* bhhb = (const float*)d_in[12];
    const float* wout = (const float*)d_in[13];
    const float* bout = (const float*)d_in[14];
    const float* trn  = (const float*)d_in[15];

    char* ws = (char*)d_ws;
    u16*   hfp    = (u16*)(ws);                       //  8,388,608 B
    u16*   hbp    = (u16*)(ws + 8388608);             //  8,388,608 B
    float* feats  = (float*)(ws + 16777216);          //    917,504 B
    float* chunkM = (float*)(ws + 17694720);          //    100,352 B

    hipMemsetAsync(d_out, 0, 4, stream);
    k_lstm<<<8, 512, 0, stream>>>(sent, emb, h0, c0, whhf, whhb, wihf, wihb,
                                  bihf, bhhf, bihb, bhhb, hfp, hbp);
    k_feats<<<1024, 256, 0, stream>>>(hfp, hbp, wout, bout, feats);
    k_crf_chunk<<<512, 64, 0, stream>>>(feats, trn, chunkM);
    k_crf_final<<<64, 64, 0, stream>>>(chunkM, trn, tags, feats, (float*)d_out);
}